// Round 17
// baseline (434.477 us; speedup 1.0000x reference)
//
#include <hip/hip_runtime.h>

#define B_  8
#define S_  4096
#define D_  768
#define H_  12
#define M_  (B_ * S_)      // 32768
#define NQKV_ 2304         // 3*D
#define NTILES 12          // 768 / 64

typedef unsigned short u16;
typedef __attribute__((ext_vector_type(4))) float  f32x4;
typedef __attribute__((ext_vector_type(8))) __bf16 bf16x8;
typedef __attribute__((ext_vector_type(4))) u16    u16x4;

#define GAS __attribute__((address_space(1)))
#define LAS __attribute__((address_space(3)))

__device__ __forceinline__ u16 f2bf(float f) {
    unsigned u = __float_as_uint(f);
    u += 0x7FFF + ((u >> 16) & 1);          // round-to-nearest-even
    return (u16)(u >> 16);
}
__device__ __forceinline__ float bf2f(u16 h) {
    return __uint_as_float(((unsigned)h) << 16);
}

__device__ __forceinline__ void gload_lds16(const void* g, void* l) {
    __builtin_amdgcn_global_load_lds((const GAS void*)g, (LAS void*)l, 16, 0, 0);
}

// bijective XCD swizzle (nwg % 8 == 0): each XCD gets a contiguous work chunk
__device__ __forceinline__ int xcd_swz(int bid, int nwg) {
    return (bid & 7) * (nwg >> 3) + (bid >> 3);
}

// ---------------- cast x (f32 -> bf16) ----------------
__global__ __launch_bounds__(256) void castx_kernel(const float* __restrict__ x,
                                                    u16* __restrict__ xb) {
    const int i = blockIdx.x * 256 + threadIdx.x;
    const float4 v = ((const float4*)x)[i];
    u16x4 o;
    o.x = f2bf(v.x); o.y = f2bf(v.y); o.z = f2bf(v.z); o.w = f2bf(v.w);
    ((u16x4*)xb)[i] = o;
}

// ---------------- weight transpose+cast: W[k][n] f32 -> Wb[n][k] bf16 ----------------
__global__ __launch_bounds__(256) void wtrans_kernel(const float* __restrict__ Wq,
                                                     const float* __restrict__ Wk,
                                                     const float* __restrict__ Wv,
                                                     const float* __restrict__ Wo,
                                                     u16* __restrict__ Wb) {
    const float* W = (blockIdx.z == 0) ? Wq : (blockIdx.z == 1) ? Wk
                   : (blockIdx.z == 2) ? Wv : Wo;
    u16* O = Wb + (size_t)blockIdx.z * D_ * D_;
    __shared__ float tile[32][33];
    const int tx = threadIdx.x & 31, ty = threadIdx.x >> 5;  // 32x8
    const int k0 = blockIdx.y * 32, n0 = blockIdx.x * 32;
#pragma unroll
    for (int j = 0; j < 4; j++)
        tile[ty + j * 8][tx] = W[(size_t)(k0 + ty + j * 8) * D_ + n0 + tx];
    __syncthreads();
#pragma unroll
    for (int j = 0; j < 4; j++)
        O[(size_t)(n0 + ty + j * 8) * D_ + k0 + tx] = f2bf(tile[tx][ty + j * 8]);
}

// === 128x128 bf16 MFMA GEMM — A via LDS (swizzled), B DIRECT from global ===
// R16 post-mortem closed the model: 64 ds_read_b128/CU/block-K-tile x 12cyc
// = 768 cyc is ~50% of the 1522-cyc wall (MfmaUtil 37% = 620cyc MFMA).
// => Halve the ds_read stream: B fragments load straight from global (L1/L2-
// resident weight panel; geometry correctness-verified in R15's B path).
// A keeps the proven gload_lds + 0-conflict swizzle. LDS = 32 KiB (A only,
// double buffer). B double-set registers; full-drain __syncthreads per K-tile
// (vmcnt(0) inside barrier ensures prefetched B regs landed -> race-free).
// 256 thr = 4 waves (2M x 2N), per-wave C = 64x64 (acc 64), ~170 VGPR.

#define MFMA8K(AF, BS, KH)                                                   \
    __builtin_amdgcn_s_setprio(1);                                           \
    _Pragma("unroll") for (int mi = 0; mi < 4; ++mi)                         \
        _Pragma("unroll") for (int ni = 0; ni < 4; ++ni)                     \
            acc[mi][ni] = __builtin_amdgcn_mfma_f32_16x16x32_bf16(           \
                AF[mi], BS[ni][KH], acc[mi][ni], 0, 0, 0);                   \
    __builtin_amdgcn_s_setprio(0)

#define LOAD_B(SEL, kt)                                                      \
    _Pragma("unroll") for (int ni = 0; ni < 4; ++ni)                         \
        _Pragma("unroll") for (int kh = 0; kh < 2; ++kh)                     \
            B2[SEL][ni][kh] = *(const bf16x8*)(Bp + (size_t)ni * 16 * D_     \
                                               + (kt) * 64 + kh * 32)

#define RD(p, imm) (*(const bf16x8*)((p) + (imm)))

template <int MODE>
__global__ __launch_bounds__(256, 2) void gemm2_kernel(
    const u16* __restrict__ A, const u16* __restrict__ Wb,
    const float* __restrict__ b0, const float* __restrict__ b1,
    const float* __restrict__ b2,
    u16* __restrict__ outb, const u16* __restrict__ xres) {
    __shared__ char lds[32768];      // A only: 2 buffers x 128 rows x 128B

    const int t = threadIdx.x;
    const int w = t >> 6, l = t & 63;
    const int wm = w >> 1, wn = w & 1;

    const int NTN = (MODE == 0) ? 18 : 6;
    const int work = xcd_swz(blockIdx.x, gridDim.x);
    const int mt = work / NTN, nt = work % NTN;   // nt fastest: A L2-reuse in XCD
    const int m0 = mt * 128;
    const int col0 = nt * 128;                    // output column base
    const int widx = (MODE == 0) ? (nt / 6) : 3;
    const int n0w  = (MODE == 0) ? (nt % 6) * 128 : col0;  // weight-row base

    // ---- A staging geometry (pre-swizzled source; 128B rows, 8 slots) ----
    const int srow = w * 32 + (l >> 3);
    const int schunk = (l & 7) ^ ((l >> 3) & 7);
    const u16* Asrc = A + (size_t)(m0 + srow) * D_ + schunk * 8;
    char* const dstA = lds + w * 4096;            // + buf*16384 + g*1024

    // ---- A ds_read geometry (swizzled slot; verified 0-conflict) ----
    const int fr = l & 15;
    const int kg = l >> 4;
    const int ck0 = ((kg ^ (l & 7)) << 4);             // kh0 slot byte
    const int ck1 = (((kg + 4) ^ (l & 7)) << 4);       // kh1 slot byte
    const char* aB = lds + (wm * 64 + fr) * 128;       // +buf +mi*2048

    // ---- B direct-from-global geometry (R15-verified fragment path) ----
    const u16* Bp = Wb + (size_t)widx * (D_ * D_)
                       + (size_t)(n0w + wn * 64 + fr) * D_ + kg * 8;

    f32x4 acc[4][4];
#pragma unroll
    for (int i = 0; i < 4; i++)
#pragma unroll
        for (int j = 0; j < 4; j++) acc[i][j] = (f32x4){0.f, 0.f, 0.f, 0.f};

    bf16x8 B2[2][4][2];   // double register set; SEL is compile-time (unrolled)

    // stage A K-tile tk into buffer b (per wave: 4 gloads, 8 rows each)
    auto STAGE_A = [&](int tk, int b) {
        const int ko = tk * 64;
        char* da = dstA + b * 16384;
#pragma unroll
        for (int g = 0; g < 4; ++g)
            gload_lds16(Asrc + ko + g * 8 * D_, da + g * 1024);
    };

    // ---- prologue ----
    STAGE_A(0, 0);
    LOAD_B(0, 0);
    __syncthreads();

#pragma unroll
    for (int X = 0; X < NTILES; ++X) {
        const int cb = (X & 1) * 16384;
        if (X + 1 < NTILES) {
            STAGE_A(X + 1, (X & 1) ^ 1);
            LOAD_B((X + 1) & 1, X + 1);
        }

        bf16x8 af[4];
        // kh0
#pragma unroll
        for (int mi = 0; mi < 4; ++mi) af[mi] = RD(aB, cb + mi * 2048 + ck0);
        MFMA8K(af, B2[X & 1], 0);
        // kh1
#pragma unroll
        for (int mi = 0; mi < 4; ++mi) af[mi] = RD(aB, cb + mi * 2048 + ck1);
        MFMA8K(af, B2[X & 1], 1);

        __syncthreads();   // full drain: vmcnt(0)+lgkm(0)+barrier (race-free)
    }

    // ---- epilogue ----
    const int crow0 = m0 + wm * 64 + (kg << 2);
    const int ccol0 = col0 + wn * 64 + fr;
    if (MODE == 0) {
        const float* bias = (widx == 0) ? b0 : (widx == 1) ? b1 : b2;
        const int bcol0 = ccol0 - widx * D_;
#pragma unroll
        for (int mi = 0; mi < 4; ++mi)
#pragma unroll
            for (int ni = 0; ni < 4; ++ni) {
                const float bv = bias[bcol0 + ni * 16];
#pragma unroll
                for (int r = 0; r < 4; ++r)
                    outb[(size_t)(crow0 + mi * 16 + r) * NQKV_ + ccol0 + ni * 16] =
                        f2bf(acc[mi][ni][r] + bv);
            }
    } else {
#pragma unroll
        for (int mi = 0; mi < 4; ++mi)
#pragma unroll
            for (int ni = 0; ni < 4; ++ni) {
                const int col = ccol0 + ni * 16;
                const float bv = b0[col];
#pragma unroll
                for (int r = 0; r < 4; ++r) {
                    const size_t idx = (size_t)(crow0 + mi * 16 + r) * D_ + col;
                    outb[idx] = f2bf(acc[mi][ni][r] + bv + bf2f(xres[idx]));
                }
            }
    }
}

// ---------------- local attention: one wave per (m, head-quad) ----------------
__global__ __launch_bounds__(256) void attn_kernel(const u16* __restrict__ QKV,
                                                   const float* __restrict__ bk,
                                                   const float* __restrict__ bv,
                                                   u16* __restrict__ att) {
    const int gw = xcd_swz(blockIdx.x, gridDim.x) * 4 + (threadIdx.x >> 6);
    const int l  = threadIdx.x & 63;
    const int hq = gw % 3;             // head-quad index
    const int m  = gw / 3;
    const int s  = m & (S_ - 1);
    const int col = hq * 256 + l * 4;
    const u16* base = QKV + (size_t)m * NQKV_;

    const u16x4 qv = *(const u16x4*)(base + col);
    float qf[4];
#pragma unroll
    for (int j = 0; j < 4; j++) qf[j] = bf2f(qv[j]);

    float sc[5];
#pragma unroll
    for (int i = 0; i < 5; i++) {
        const int sp = s + i - 2;
        float p;
        if (sp >= 0 && sp < S_) {
            const u16x4 kv = *(const u16x4*)(base + (i - 2) * NQKV_ + D_ + col);
            p = qf[0] * bf2f(kv[0]) + qf[1] * bf2f(kv[1])
              + qf[2] * bf2f(kv[2]) + qf[3] * bf2f(kv[3]);
        } else {
            const float4 kb = *(const float4*)(bk + col);
            p = qf[0] * kb.x + qf[1] * kb.y + qf[2] * kb.z + qf[3] * kb.w;
        }
#pragma unroll
        for (int off = 1; off < 16; off <<= 1) p += __shfl_xor(p, off, 64);
        sc[i] = p * 0.125f;
    }
    float mx = sc[0];
#pragma unroll
    for (int i = 1; i < 5; i++) mx = fmaxf(mx, sc[i]);
    float e[5], sum = 0.f;
#pragma unroll
    for (int i = 0; i < 5; i++) { e[i] = __expf(sc[i] - mx); sum += e[i]; }
    const float inv = 1.f / sum;

    float o[4] = {0.f, 0.f, 0.f, 0.f};
#pragma unroll
    for (int i = 0; i < 5; i++) {
        const float wgt = e[i] * inv;
        const int sp = s + i - 2;
        if (sp >= 0 && sp < S_) {
            const u16x4 vv = *(const u16x4*)(base + (i - 2) * NQKV_ + 2 * D_ + col);
#pragma unroll
            for (int j = 0; j < 4; j++) o[j] += wgt * bf2f(vv[j]);
        } else {
            const float4 vb = *(const float4*)(bv + col);
            o[0] += wgt * vb.x; o[1] += wgt * vb.y;
            o[2] += wgt * vb.z; o[3] += wgt * vb.w;
        }
    }
    u16x4 ov;
#pragma unroll
    for (int j = 0; j < 4; j++) ov[j] = f2bf(o[j]);
    *(u16x4*)(att + (size_t)m * D_ + col) = ov;
}

// ------- LayerNorm, wave-per-row (vectorized bf16 loads, no LDS/barrier) -------
__global__ __launch_bounds__(256) void ln_kernel(const u16* __restrict__ Yb,
                                                 const float* __restrict__ gamma,
                                                 const float* __restrict__ beta,
                                                 float* __restrict__ out) {
    const int w = threadIdx.x >> 6, l = threadIdx.x & 63;
    const int row = blockIdx.x * 4 + w;
    const u16* r = Yb + (size_t)row * D_;
    const int c0 = l * 4;

    float v[3][4];
    float s = 0.f, s2 = 0.f;
#pragma unroll
    for (int c = 0; c < 3; ++c) {
        const u16x4 hv = *(const u16x4*)(r + c * 256 + c0);
#pragma unroll
        for (int j = 0; j < 4; ++j) {
            const float f = bf2f(hv[j]);
            v[c][j] = f;
            s += f;
            s2 += f * f;
        }
    }
#pragma unroll
    for (int off = 1; off < 64; off <<= 1) {
        s  += __shfl_xor(s,  off, 64);
        s2 += __shfl_xor(s2, off, 64);
    }
    const float mu  = s * (1.f / 768.f);
    const float var = s2 * (1.f / 768.f) - mu * mu;
    const float inv = rsqrtf(var + 1e-5f);

    float* o = out + (size_t)row * D_;
#pragma unroll
    for (int c = 0; c < 3; ++c) {
        const float4 g = *(const float4*)(gamma + c * 256 + c0);
        const float4 b = *(const float4*)(beta  + c * 256 + c0);
        float4 ov;
        ov.x = (v[c][0] - mu) * inv * g.x + b.x;
        ov.y = (v[c][1] - mu) * inv * g.y + b.y;
        ov.z = (v[c][2] - mu) * inv * g.z + b.z;
        ov.w = (v[c][3] - mu) * inv * g.w + b.w;
        *(float4*)(o + c * 256 + c0) = ov;
    }
}

extern "C" void kernel_launch(void* const* d_in, const int* in_sizes, int n_in,
                              void* d_out, int out_size, void* d_ws, size_t ws_size,
                              hipStream_t stream) {
    const float* x     = (const float*)d_in[0];
    const float* Wq    = (const float*)d_in[1];
    const float* bq    = (const float*)d_in[2];
    const float* Wk    = (const float*)d_in[3];
    const float* bk    = (const float*)d_in[4];
    const float* Wv    = (const float*)d_in[5];
    const float* bv    = (const float*)d_in[6];
    const float* Wo    = (const float*)d_in[7];
    const float* bo    = (const float*)d_in[8];
    const float* gamma = (const float*)d_in[9];
    const float* beta  = (const float*)d_in[10];

    char* ws = (char*)d_ws;
    u16*   Wb  = (u16*)ws;                                  //  4,718,592 B
    u16*   xb  = (u16*)(ws + 4718592);                      // 50,331,648 B (stays live)
    u16*   QKV = (u16*)(ws + 4718592 + 50331648);           // 150,994,944 B
    u16*   yb  = QKV;                                       // reuse after attn
    u16*   att = (u16*)d_out;                               // scratch in d_out

    castx_kernel<<<(M_ * D_) / (256 * 4), 256, 0, stream>>>(x, xb);
    wtrans_kernel<<<dim3(24, 24, 4), 256, 0, stream>>>(Wq, Wk, Wv, Wo, Wb);
    gemm2_kernel<0><<<(M_ / 128) * 18, 256, 0, stream>>>(xb, Wb, bq, bk, bv,
                                                         QKV, nullptr);
    attn_kernel<<<(M_ * 3) / 4, 256, 0, stream>>>(QKV, bk, bv, att);
    gemm2_kernel<1><<<(M_ / 128) * 6, 256, 0, stream>>>(att, Wb, bo, nullptr, nullptr,
                                                        yb, xb);
    ln_kernel<<<M_ / 4, 256, 0, stream>>>(yb, gamma, beta, (float*)d_out);
}

// Round 18
// 289.500 us; speedup vs baseline: 1.5008x; 1.5008x over previous
//
#include <hip/hip_runtime.h>

#define B_  8
#define S_  4096
#define D_  768
#define H_  12
#define M_  (B_ * S_)      // 32768
#define NQKV_ 2304         // 3*D
#define NTILES 12          // 768 / 64

typedef unsigned short u16;
typedef __attribute__((ext_vector_type(4))) float  f32x4;
typedef __attribute__((ext_vector_type(8))) __bf16 bf16x8;
typedef __attribute__((ext_vector_type(4))) u16    u16x4;

#define GAS __attribute__((address_space(1)))
#define LAS __attribute__((address_space(3)))

__device__ __forceinline__ u16 f2bf(float f) {
    unsigned u = __float_as_uint(f);
    u += 0x7FFF + ((u >> 16) & 1);          // round-to-nearest-even
    return (u16)(u >> 16);
}
__device__ __forceinline__ float bf2f(u16 h) {
    return __uint_as_float(((unsigned)h) << 16);
}

__device__ __forceinline__ void gload_lds16(const void* g, void* l) {
    __builtin_amdgcn_global_load_lds((const GAS void*)g, (LAS void*)l, 16, 0, 0);
}

// bijective XCD swizzle (nwg % 8 == 0): each XCD gets a contiguous work chunk
__device__ __forceinline__ int xcd_swz(int bid, int nwg) {
    return (bid & 7) * (nwg >> 3) + (bid >> 3);
}

// ---------------- cast x (f32 -> bf16) ----------------
__global__ __launch_bounds__(256) void castx_kernel(const float* __restrict__ x,
                                                    u16* __restrict__ xb) {
    const int i = blockIdx.x * 256 + threadIdx.x;
    const float4 v = ((const float4*)x)[i];
    u16x4 o;
    o.x = f2bf(v.x); o.y = f2bf(v.y); o.z = f2bf(v.z); o.w = f2bf(v.w);
    ((u16x4*)xb)[i] = o;
}

// ---------------- weight transpose+cast: W[k][n] f32 -> Wb[n][k] bf16 ----------------
__global__ __launch_bounds__(256) void wtrans_kernel(const float* __restrict__ Wq,
                                                     const float* __restrict__ Wk,
                                                     const float* __restrict__ Wv,
                                                     const float* __restrict__ Wo,
                                                     u16* __restrict__ Wb) {
    const float* W = (blockIdx.z == 0) ? Wq : (blockIdx.z == 1) ? Wk
                   : (blockIdx.z == 2) ? Wv : Wo;
    u16* O = Wb + (size_t)blockIdx.z * D_ * D_;
    __shared__ float tile[32][33];
    const int tx = threadIdx.x & 31, ty = threadIdx.x >> 5;  // 32x8
    const int k0 = blockIdx.y * 32, n0 = blockIdx.x * 32;
#pragma unroll
    for (int j = 0; j < 4; j++)
        tile[ty + j * 8][tx] = W[(size_t)(k0 + ty + j * 8) * D_ + n0 + tx];
    __syncthreads();
#pragma unroll
    for (int j = 0; j < 4; j++)
        O[(size_t)(n0 + ty + j * 8) * D_ + k0 + tx] = f2bf(tile[tx][ty + j * 8]);
}

// ====== 128x128 double-buffered bf16 MFMA GEMM — per-wave 64x64, 2 blk/CU ======
// (R16 configuration verbatim — best verified total 289.9 µs; 0 bank conflicts.
//  R15/R17 refuted LDS-bypass in both directions: LDS staging is the BW
//  amplifier. This structure sits at the verified ~900 TF 2-phase ceiling.)
// 256 threads = 4 waves (2M x 2N), per-wave C = 64x64 (acc 64 f32), BK=64.
// LDS 64 KiB = 2 buffers x (A 128rows x 128B + B 128rows x 128B).
// Swizzle (VERIFIED 0-conflict): LDS slot s of row R holds global 16B-chunk
//   s ^ (R&7); staging pre-swizzles the source; reads use swizzled slot.
// Schedule: per K-tile { stage X+1 -> other buf; ds_read+MFMA from current;
//   __syncthreads() } — full drain (no counted-vmcnt race class).

#define MFMA16(AF, BF)                                                       \
    __builtin_amdgcn_s_setprio(1);                                           \
    _Pragma("unroll") for (int mi = 0; mi < 4; ++mi)                         \
        _Pragma("unroll") for (int ni = 0; ni < 4; ++ni)                     \
            acc[mi][ni] = __builtin_amdgcn_mfma_f32_16x16x32_bf16(           \
                AF[mi], BF[ni], acc[mi][ni], 0, 0, 0);                       \
    __builtin_amdgcn_s_setprio(0)

#define RD(p, imm) (*(const bf16x8*)((p) + (imm)))

template <int MODE>
__global__ __launch_bounds__(256, 2) void gemm2_kernel(
    const u16* __restrict__ A, const u16* __restrict__ Wb,
    const float* __restrict__ b0, const float* __restrict__ b1,
    const float* __restrict__ b2,
    u16* __restrict__ outb, const u16* __restrict__ xres) {
    extern __shared__ char lds[];    // 65536 B

    const int t = threadIdx.x;
    const int w = t >> 6, l = t & 63;
    const int wm = w >> 1, wn = w & 1;

    const int NTN = (MODE == 0) ? 18 : 6;
    const int work = xcd_swz(blockIdx.x, gridDim.x);
    const int mt = work / NTN, nt = work % NTN;   // nt fastest: A L2-reuse in XCD
    const int m0 = mt * 128;
    const int col0 = nt * 128;                    // output column base
    const int widx = (MODE == 0) ? (nt / 6) : 3;
    const int n0w  = (MODE == 0) ? (nt % 6) * 128 : col0;  // weight-row base

    // ---- staging geometry (pre-swizzled source; 128B rows, 8 slots) ----
    const int srow = w * 32 + (l >> 3);
    const int schunk = (l & 7) ^ ((l >> 3) & 7);
    const u16* Asrc = A + (size_t)(m0 + srow) * D_ + schunk * 8;
    const u16* Bsrc = Wb + (size_t)widx * (D_ * D_)
                         + (size_t)(n0w + srow) * D_ + schunk * 8;
    char* const dstA = lds + w * 4096;            // + buf*32768 + g*1024
    char* const dstB = lds + 16384 + w * 4096;

    // ---- ds_read geometry (swizzled slot; verified pattern) ----
    const int ck0 = (((l >> 4) ^ (l & 7)) << 4);         // kh0 slot byte
    const int ck1 = ((((l >> 4) + 4) ^ (l & 7)) << 4);   // kh1 slot byte
    const char* aB = lds + (wm * 64 + (l & 15)) * 128;           // +buf +mi*2048
    const char* bB = lds + 16384 + (wn * 64 + (l & 15)) * 128;   // +buf +ni*2048

    f32x4 acc[4][4];
#pragma unroll
    for (int i = 0; i < 4; i++)
#pragma unroll
        for (int j = 0; j < 4; j++) acc[i][j] = (f32x4){0.f, 0.f, 0.f, 0.f};

    // stage K-tile tk into buffer b (per wave: 4 A + 4 B gloads, 8 rows each)
    auto STAGE = [&](int tk, int b) {
        const int ko = tk * 64;                  // element offset along K
        char* da = dstA + b * 32768;
        char* db = dstB + b * 32768;
#pragma unroll
        for (int g = 0; g < 4; ++g) {
            gload_lds16(Asrc + ko + g * 8 * D_, da + g * 1024);
            gload_lds16(Bsrc + ko + g * 8 * D_, db + g * 1024);
        }
    };

    // ---- prologue ----
    STAGE(0, 0);
    __syncthreads();

#pragma unroll
    for (int X = 0; X < NTILES; ++X) {
        const int cb = (X & 1) * 32768;
        if (X + 1 < NTILES) STAGE(X + 1, (X & 1) ^ 1);

        bf16x8 af[4], bf[4];
        // kh0
#pragma unroll
        for (int mi = 0; mi < 4; ++mi) af[mi] = RD(aB, cb + mi * 2048 + ck0);
#pragma unroll
        for (int ni = 0; ni < 4; ++ni) bf[ni] = RD(bB, cb + ni * 2048 + ck0);
        MFMA16(af, bf);
        // kh1
#pragma unroll
        for (int mi = 0; mi < 4; ++mi) af[mi] = RD(aB, cb + mi * 2048 + ck1);
#pragma unroll
        for (int ni = 0; ni < 4; ++ni) bf[ni] = RD(bB, cb + ni * 2048 + ck1);
        MFMA16(af, bf);

        __syncthreads();   // full drain: vmcnt(0)+lgkm(0)+barrier (race-free)
    }

    // ---- epilogue ----
    const int crow0 = m0 + wm * 64 + ((l >> 4) << 2);
    const int ccol0 = col0 + wn * 64 + (l & 15);
    if (MODE == 0) {
        const float* bias = (widx == 0) ? b0 : (widx == 1) ? b1 : b2;
        const int bcol0 = ccol0 - widx * D_;
#pragma unroll
        for (int mi = 0; mi < 4; ++mi)
#pragma unroll
            for (int ni = 0; ni < 4; ++ni) {
                const float bv = bias[bcol0 + ni * 16];
#pragma unroll
                for (int r = 0; r < 4; ++r)
                    outb[(size_t)(crow0 + mi * 16 + r) * NQKV_ + ccol0 + ni * 16] =
                        f2bf(acc[mi][ni][r] + bv);
            }
    } else {
#pragma unroll
        for (int mi = 0; mi < 4; ++mi)
#pragma unroll
            for (int ni = 0; ni < 4; ++ni) {
                const int col = ccol0 + ni * 16;
                const float bv = b0[col];
#pragma unroll
                for (int r = 0; r < 4; ++r) {
                    const size_t idx = (size_t)(crow0 + mi * 16 + r) * D_ + col;
                    outb[idx] = f2bf(acc[mi][ni][r] + bv + bf2f(xres[idx]));
                }
            }
    }
}

// ---------------- local attention: one wave per (m, head-quad) ----------------
__global__ __launch_bounds__(256) void attn_kernel(const u16* __restrict__ QKV,
                                                   const float* __restrict__ bk,
                                                   const float* __restrict__ bv,
                                                   u16* __restrict__ att) {
    const int gw = xcd_swz(blockIdx.x, gridDim.x) * 4 + (threadIdx.x >> 6);
    const int l  = threadIdx.x & 63;
    const int hq = gw % 3;             // head-quad index
    const int m  = gw / 3;
    const int s  = m & (S_ - 1);
    const int col = hq * 256 + l * 4;
    const u16* base = QKV + (size_t)m * NQKV_;

    const u16x4 qv = *(const u16x4*)(base + col);
    float qf[4];
#pragma unroll
    for (int j = 0; j < 4; j++) qf[j] = bf2f(qv[j]);

    float sc[5];
#pragma unroll
    for (int i = 0; i < 5; i++) {
        const int sp = s + i - 2;
        float p;
        if (sp >= 0 && sp < S_) {
            const u16x4 kv = *(const u16x4*)(base + (i - 2) * NQKV_ + D_ + col);
            p = qf[0] * bf2f(kv[0]) + qf[1] * bf2f(kv[1])
              + qf[2] * bf2f(kv[2]) + qf[3] * bf2f(kv[3]);
        } else {
            const float4 kb = *(const float4*)(bk + col);
            p = qf[0] * kb.x + qf[1] * kb.y + qf[2] * kb.z + qf[3] * kb.w;
        }
#pragma unroll
        for (int off = 1; off < 16; off <<= 1) p += __shfl_xor(p, off, 64);
        sc[i] = p * 0.125f;
    }
    float mx = sc[0];
#pragma unroll
    for (int i = 1; i < 5; i++) mx = fmaxf(mx, sc[i]);
    float e[5], sum = 0.f;
#pragma unroll
    for (int i = 0; i < 5; i++) { e[i] = __expf(sc[i] - mx); sum += e[i]; }
    const float inv = 1.f / sum;

    float o[4] = {0.f, 0.f, 0.f, 0.f};
#pragma unroll
    for (int i = 0; i < 5; i++) {
        const float wgt = e[i] * inv;
        const int sp = s + i - 2;
        if (sp >= 0 && sp < S_) {
            const u16x4 vv = *(const u16x4*)(base + (i - 2) * NQKV_ + 2 * D_ + col);
#pragma unroll
            for (int j = 0; j < 4; j++) o[j] += wgt * bf2f(vv[j]);
        } else {
            const float4 vb = *(const float4*)(bv + col);
            o[0] += wgt * vb.x; o[1] += wgt * vb.y;
            o[2] += wgt * vb.z; o[3] += wgt * vb.w;
        }
    }
    u16x4 ov;
#pragma unroll
    for (int j = 0; j < 4; j++) ov[j] = f2bf(o[j]);
    *(u16x4*)(att + (size_t)m * D_ + col) = ov;
}

// ------- LayerNorm, wave-per-row (vectorized bf16 loads, no LDS/barrier) -------
__global__ __launch_bounds__(256) void ln_kernel(const u16* __restrict__ Yb,
                                                 const float* __restrict__ gamma,
                                                 const float* __restrict__ beta,
                                                 float* __restrict__ out) {
    const int w = threadIdx.x >> 6, l = threadIdx.x & 63;
    const int row = blockIdx.x * 4 + w;
    const u16* r = Yb + (size_t)row * D_;
    const int c0 = l * 4;

    float v[3][4];
    float s = 0.f, s2 = 0.f;
#pragma unroll
    for (int c = 0; c < 3; ++c) {
        const u16x4 hv = *(const u16x4*)(r + c * 256 + c0);
#pragma unroll
        for (int j = 0; j < 4; ++j) {
            const float f = bf2f(hv[j]);
            v[c][j] = f;
            s += f;
            s2 += f * f;
        }
    }
#pragma unroll
    for (int off = 1; off < 64; off <<= 1) {
        s  += __shfl_xor(s,  off, 64);
        s2 += __shfl_xor(s2, off, 64);
    }
    const float mu  = s * (1.f / 768.f);
    const float var = s2 * (1.f / 768.f) - mu * mu;
    const float inv = rsqrtf(var + 1e-5f);

    float* o = out + (size_t)row * D_;
#pragma unroll
    for (int c = 0; c < 3; ++c) {
        const float4 g = *(const float4*)(gamma + c * 256 + c0);
        const float4 b = *(const float4*)(beta  + c * 256 + c0);
        float4 ov;
        ov.x = (v[c][0] - mu) * inv * g.x + b.x;
        ov.y = (v[c][1] - mu) * inv * g.y + b.y;
        ov.z = (v[c][2] - mu) * inv * g.z + b.z;
        ov.w = (v[c][3] - mu) * inv * g.w + b.w;
        *(float4*)(o + c * 256 + c0) = ov;
    }
}

extern "C" void kernel_launch(void* const* d_in, const int* in_sizes, int n_in,
                              void* d_out, int out_size, void* d_ws, size_t ws_size,
                              hipStream_t stream) {
    const float* x     = (const float*)d_in[0];
    const float* Wq    = (const float*)d_in[1];
    const float* bq    = (const float*)d_in[2];
    const float* Wk    = (const float*)d_in[3];
    const float* bk    = (const float*)d_in[4];
    const float* Wv    = (const float*)d_in[5];
    const float* bv    = (const float*)d_in[6];
    const float* Wo    = (const float*)d_in[7];
    const float* bo    = (const float*)d_in[8];
    const float* gamma = (const float*)d_in[9];
    const float* beta  = (const float*)d_in[10];

    char* ws = (char*)d_ws;
    u16*   Wb  = (u16*)ws;                                  //  4,718,592 B
    u16*   xb  = (u16*)(ws + 4718592);                      // 50,331,648 B (stays live)
    u16*   QKV = (u16*)(ws + 4718592 + 50331648);           // 150,994,944 B
    u16*   yb  = QKV;                                       // reuse after attn
    u16*   att = (u16*)d_out;                               // scratch in d_out

    (void)hipFuncSetAttribute(reinterpret_cast<const void*>(&gemm2_kernel<0>),
                              hipFuncAttributeMaxDynamicSharedMemorySize, 65536);
    (void)hipFuncSetAttribute(reinterpret_cast<const void*>(&gemm2_kernel<1>),
                              hipFuncAttributeMaxDynamicSharedMemorySize, 65536);

    castx_kernel<<<(M_ * D_) / (256 * 4), 256, 0, stream>>>(x, xb);
    wtrans_kernel<<<dim3(24, 24, 4), 256, 0, stream>>>(Wq, Wk, Wv, Wo, Wb);
    gemm2_kernel<0><<<(M_ / 128) * 18, 256, 65536, stream>>>(xb, Wb, bq, bk, bv,
                                                             QKV, nullptr);
    attn_kernel<<<(M_ * 3) / 4, 256, 0, stream>>>(QKV, bk, bv, att);
    gemm2_kernel<1><<<(M_ / 128) * 6, 256, 65536, stream>>>(att, Wb, bo, nullptr, nullptr,
                                                            yb, xb);
    ln_kernel<<<M_ / 4, 256, 0, stream>>>(yb, gamma, beta, (float*)d_out);
}